// Round 12
// baseline (131.668 us; speedup 1.0000x reference)
//
#include <hip/hip_runtime.h>
#include <hip/hip_bf16.h>
#include <math.h>

#define IMG 512
#define TW 64                     // output tile width
#define TH 32                     // output tile height
#define NTX 8
#define NTY 16
#define NIMG 48
#define TPB 12                    // tiles per block
#define NPBLK 512                 // 512 blocks = 2/CU exactly; 512*12 = 6144 tiles
#define NPIX (16LL * 3 * 512 * 512)

#define C1F 0.0001f
#define C2F 0.0009f

// R12 == R11 resubmission (R11 died to the same infra/container failure as
// R8 — zero dispatch rows, not even harness memsets ran; R8's identical
// resubmission R9 passed, establishing the flake precedent. Kernel
// re-audited: uniform barriers, disjoint async-write/read buffers,
// exec-masked gl_lds same as R10, LDS 57,344B < 64KB, no API calls.)
//
// R11 = R8's persistent double-buffered pipeline + R10's gl_lds staging.
// R10 win (48->41us, BW 2.0->2.3 TB/s) confirmed the in-flight-bytes model,
// but delivered rate is ~7 B/cyc/CU vs m13's ~10: each block still convoys
// {issue -> vmcnt(0) drain -> compute} ONCE, so memory idles during every
// compute phase. Fix: 12 tiles/block, double-buffered LDS. Per iteration:
//   A: issue 28 fire-and-forget gl_lds chunks for tile t+1 -> buf[cur^1]
//   B: compute tile t from buf[cur] (R10's exact path)
//   C: barrier — loads had the whole compute phase in flight => drain ~free.
// Race-free: buf[cur^1] last read in iter t-1, sealed by iter t-1 barrier;
// boundary zero-fill writes only NOT-loaded slots. 2 blocks/CU; zero tail.
// Tripwires: WRITE_SIZE >> 1MB = spill; absmax must stay 0.0078125;
// dur >= 38us clean => intra-block pipelining falsified, R10 structure wins.

#define SR 84                     // LDS row stride in floats (2-way bank alias = free)
#define SROWS 42
#define CHUNKF 256                // floats per 1KB chunk (64 lanes * 4)
#define NCHUNK 14                 // ceil(42*84/256)
#define BUFFLOATS (NCHUNK * CHUNKF)   // 3584 (incl. spare tail row; cols 80..83 pad)

typedef __attribute__((ext_vector_type(4))) short short4v;
typedef __attribute__((ext_vector_type(8))) short short8;
typedef __attribute__((ext_vector_type(4))) float float4v;
typedef __attribute__((ext_vector_type(2))) unsigned uint2v;
typedef __attribute__((ext_vector_type(4))) unsigned uint4v;

// 16x16x16 bf16 MFMA (device-verified _1k builtin on gfx950; host parse stub).
__device__ __forceinline__ float4v mfma16(short4v a, short4v b, float4v c) {
#if defined(__HIP_DEVICE_COMPILE__)
    return __builtin_amdgcn_mfma_f32_16x16x16bf16_1k(a, b, c, 0, 0, 0);
#else
    return c;   // host stub — never executed
#endif
}

// Async global->LDS 16B: lds dest = wave-uniform base + lane*16.
__device__ __forceinline__ void gl_lds16(const float* g, float* l) {
#if defined(__HIP_DEVICE_COMPILE__)
    __builtin_amdgcn_global_load_lds(
        (const __attribute__((address_space(1))) void*)g,
        (__attribute__((address_space(3))) void*)l, 16, 0, 0);
#else
    (void)g; (void)l;
#endif
}

// Gaussian window (sigma=1.5, ws=11), normalized (double-derived literals).
#define GW0 0.00102838f
#define GW1 0.00759877f
#define GW2 0.03600077f
#define GW3 0.10936069f
#define GW4 0.21300539f
#define GW5 0.26601172f

__device__ __forceinline__ unsigned short f2bf(float f) {
    unsigned u = __builtin_bit_cast(unsigned, f);
    u += 0x7FFF + ((u >> 16) & 1);            // RNE
    return (unsigned short)(u >> 16);
}
__device__ __forceinline__ unsigned pk2(float a, float b) {
    __hip_bfloat162 h = __float22bfloat162_rn(make_float2(a, b));
    unsigned u;
    __builtin_memcpy(&u, &h, 4);
    return u;
}

#define BC4(U) __builtin_bit_cast(short4v, U)

// Tile coords from tile index TT (128 tiles per image: 8 bx x 16 by).
#define TCOORD(TT, R00, C00A, XI, YI, BND)                                     \
    {                                                                          \
        const int gid_ = gbase + (TT);                                         \
        XI = xg + ((size_t)(gid_ >> 7) * (IMG * IMG));                         \
        YI = yg + ((size_t)(gid_ >> 7) * (IMG * IMG));                         \
        const int by_ = (gid_ >> 3) & 15, bx_ = gid_ & 7;                      \
        R00  = by_ * TH - 5;                                                   \
        C00A = bx_ * TW - 8;                                                   \
        BND  = !(((unsigned)(bx_ - 1) <= 5u) & ((unsigned)(by_ - 1) <= 13u));  \
    }

// Issue 28 async 1KB chunks for one tile into buffer B (7 per wave).
#define STAGE_ISSUE(B, R00, C00A, XI, YI)                                      \
    _Pragma("unroll")                                                          \
    for (int k_ = 0; k_ < 7; ++k_) {                                           \
        const int ck_ = w * 7 + k_;                  /* wave-uniform */        \
        const bool isx_ = (ck_ < NCHUNK);                                      \
        const int c_ = isx_ ? ck_ : ck_ - NCHUNK;    /* wave-uniform */        \
        const int o_ = c_ * CHUNKF + lane * 4;                                 \
        const int row_ = o_ / SR;                                              \
        const int col_ = o_ - row_ * SR;                                       \
        const int gr_ = (R00) + row_, gc_ = (C00A) + col_;                     \
        if (((unsigned)gr_ < 512u) & ((unsigned)gc_ < 512u)) {                 \
            const float* src_ = (isx_ ? (XI) : (YI)) + (size_t)gr_ * IMG + gc_;\
            float* dstb_ = (isx_ ? &xb[B][0] : &yb[B][0]) + c_ * CHUNKF;       \
            gl_lds16(src_, dstb_);                                             \
        }                                                                      \
    }

// Boundary tiles: zero exactly the NOT-loaded slots of buffer B (disjoint
// from the async gl_lds destinations -> race-free).
#define STAGE_ZERO(B, R00, C00A)                                               \
    for (int o_ = tid * 4; o_ < BUFFLOATS; o_ += 1024) {                       \
        const int row_ = o_ / SR, col_ = o_ - row_ * SR;                       \
        const int gr_ = (R00) + row_, gc_ = (C00A) + col_;                     \
        if (!(((unsigned)gr_ < 512u) & ((unsigned)gc_ < 512u))) {              \
            *(float4v*)&xb[B][o_] = z4;                                        \
            *(float4v*)&yb[B][o_] = z4;                                        \
        }                                                                      \
    }

// H-conv of one row from the f32 panels in buf[cur]: build 4 bf16 channels
// in-register (R1's exact math), 4 MFMAs into named uint2v, owned-region L1.
#define HCONV_F32(ROWE, SROWE, DX, DY, DS, DP)                                 \
    {                                                                          \
        const int srow_ = (SROWE);                                             \
        const int b_ = (ROWE) * SR + co;                                       \
        float4v x0 = *(const float4v*)&xb[cur][b_];                            \
        float4v x1 = *(const float4v*)&xb[cur][b_ + 4];                        \
        float4v y0 = *(const float4v*)&yb[cur][b_];                            \
        float4v y1 = *(const float4v*)&yb[cur][b_ + 4];                        \
        uint4v ux_ = (uint4v){pk2(x0[0], x0[1]), pk2(x0[2], x0[3]),            \
                              pk2(x1[0], x1[1]), pk2(x1[2], x1[3])};           \
        uint4v uy_ = (uint4v){pk2(y0[0], y0[1]), pk2(y0[2], y0[3]),            \
                              pk2(y1[0], y1[1]), pk2(y1[2], y1[3])};           \
        uint4v u2_ = (uint4v){                                                 \
            pk2(fmaf(x0[0],x0[0],y0[0]*y0[0]), fmaf(x0[1],x0[1],y0[1]*y0[1])), \
            pk2(fmaf(x0[2],x0[2],y0[2]*y0[2]), fmaf(x0[3],x0[3],y0[3]*y0[3])), \
            pk2(fmaf(x1[0],x1[0],y1[0]*y1[0]), fmaf(x1[1],x1[1],y1[1]*y1[1])), \
            pk2(fmaf(x1[2],x1[2],y1[2]*y1[2]), fmaf(x1[3],x1[3],y1[3]*y1[3]))};\
        uint4v u3_ = (uint4v){                                                 \
            pk2(x0[0]*y0[0], x0[1]*y0[1]), pk2(x0[2]*y0[2], x0[3]*y0[3]),      \
            pk2(x1[0]*y1[0], x1[1]*y1[1]), pk2(x1[2]*y1[2], x1[3]*y1[3])};     \
        float4v d_;                                                            \
        d_ = __builtin_amdgcn_mfma_f32_16x16x32_bf16(                          \
                 __builtin_bit_cast(short8, ux_), bh, zero4, 0, 0, 0);         \
        DX = (uint2v){pk2(d_[0], d_[1]), pk2(d_[2], d_[3])};                   \
        d_ = __builtin_amdgcn_mfma_f32_16x16x32_bf16(                          \
                 __builtin_bit_cast(short8, uy_), bh, zero4, 0, 0, 0);         \
        DY = (uint2v){pk2(d_[0], d_[1]), pk2(d_[2], d_[3])};                   \
        d_ = __builtin_amdgcn_mfma_f32_16x16x32_bf16(                          \
                 __builtin_bit_cast(short8, u2_), bh, zero4, 0, 0, 0);         \
        DS = (uint2v){pk2(d_[0], d_[1]), pk2(d_[2], d_[3])};                   \
        d_ = __builtin_amdgcn_mfma_f32_16x16x32_bf16(                          \
                 __builtin_bit_cast(short8, u3_), bh, zero4, 0, 0, 0);         \
        DP = (uint2v){pk2(d_[0], d_[1]), pk2(d_[2], d_[3])};                   \
        if ((unsigned)(q - 1) <= 1u && (unsigned)(srow_ - 5) <= 31u)           \
            l1_loc += fabsf(x0[0]-y0[0])+fabsf(x0[1]-y0[1])                    \
                    + fabsf(x0[2]-y0[2])+fabsf(x0[3]-y0[3])                    \
                    + fabsf(x1[0]-y1[0])+fabsf(x1[1]-y1[1])                    \
                    + fabsf(x1[2]-y1[2])+fabsf(x1[3]-y1[3]);                   \
    }

// SSIM epilogue over one float4v set.
#define SSIM_ACC(M1, M2, EE, PP)                                               \
    _Pragma("unroll")                                                          \
    for (int r_ = 0; r_ < 4; ++r_) {                                           \
        float mu1 = (M1)[r_], mu2 = (M2)[r_];                                  \
        float e   = (EE)[r_], e12 = (PP)[r_];                                  \
        float p = mu1 * mu2;                                                   \
        float s = fmaf(mu1, mu1, mu2 * mu2);                                   \
        float num1 = fmaf(2.f, p, C1F);                                        \
        float num2 = fmaf(2.f, e12 - p, C2F);                                  \
        float den1 = s + C1F;                                                  \
        float den2 = (e - s) + C2F;                                            \
        ssim_loc = fmaf(num1 * num2,                                           \
                        __builtin_amdgcn_rcpf(den1 * den2), ssim_loc);         \
    }

__global__ __launch_bounds__(256, 2)
void ssim_pipe_kernel(const float* __restrict__ xg, const float* __restrict__ yg,
                      float* __restrict__ partials) {
    __shared__ float xb[2][BUFFLOATS];              // 28,672 B
    __shared__ float yb[2][BUFFLOATS];              // 28,672 B
    __shared__ unsigned short gwtbl[16];
    __shared__ float red[8];

    const int tid  = threadIdx.x;
    const int lane = tid & 63;
    const int w    = tid >> 6;        // wave 0..3 = colgroup
    const int q    = lane >> 4;       // quad 0..3
    const int n16  = lane & 15;

    // ---- bf16 Gaussian tap table ----
    if (tid < 16) {
        const float gwf[11] = {GW0, GW1, GW2, GW3, GW4, GW5, GW4, GW3, GW2, GW1, GW0};
        unsigned short v = 0;
        #pragma unroll
        for (int t = 0; t < 11; ++t)
            if (tid == t) v = f2bf(gwf[t]);
        gwtbl[tid] = v;
    }
    __syncthreads();

    // ---- B fragments, hoisted once for all 12 tiles ----
    short8 bh;
    short4v bv0, bv1;
    {
        int baseh = q * 8 - n16 - 3;
        #pragma unroll
        for (int j = 0; j < 8; ++j)
            bh[j] = (short)gwtbl[min((unsigned)(baseh + j), 15u)];
        int base0 = q * 4 - n16, base1 = q * 4 + 16 - n16;
        #pragma unroll
        for (int j = 0; j < 4; ++j) {
            bv0[j] = (short)gwtbl[min((unsigned)(base0 + j), 15u)];
            bv1[j] = (short)gwtbl[min((unsigned)(base1 + j), 15u)];
        }
    }

    const int gbase = blockIdx.x * TPB;
    const int co = w * 16 + q * 8;
    const float4v zero4 = {0.f, 0.f, 0.f, 0.f};
    const float4v z4 = {0.f, 0.f, 0.f, 0.f};
    float l1_loc = 0.f, ssim_loc = 0.f;

    // ---- Prologue: stage tile 0 into buf 0 ----
    {
        const float *xi0, *yi0; int r00p, c00p; bool bnd0;
        TCOORD(0, r00p, c00p, xi0, yi0, bnd0)
        STAGE_ISSUE(0, r00p, c00p, xi0, yi0)
        if (bnd0) STAGE_ZERO(0, r00p, c00p)
    }
    __syncthreads();   // drain tile-0 loads

    int cur = 0;
    for (int t = 0; t < TPB; ++t) {
        // ---- Phase A: issue tile t+1 -> buf[cur^1] (flies during compute) --
        if (t + 1 < TPB) {
            const float *nxi, *nyi; int nr00, nc00a; bool nbnd;
            TCOORD(t + 1, nr00, nc00a, nxi, nyi, nbnd)
            STAGE_ISSUE(cur ^ 1, nr00, nc00a, nxi, nyi)
            if (nbnd) STAGE_ZERO(cur ^ 1, nr00, nc00a)
        }

        // ---- Phase B: compute tile t from buf[cur] (R10's exact path) ----
        {
            uint2v d0x, d0y, d0s, d0p;      // rg0
            uint2v e1x, e1y, e1s, e1p;      // rg1
            uint2v f2x, f2y, f2s, f2p;      // rg2 (rows >41 clamp: zero v-taps)
            HCONV_F32(n16,               n16,      d0x, d0y, d0s, d0p)
            HCONV_F32(16 + n16,          16 + n16, e1x, e1y, e1s, e1p)
            HCONV_F32(min(32 + n16, 41), 32 + n16, f2x, f2y, f2s, f2p)

            {   // rgp = 0
                float4v am1 = mfma16(BC4(d0x), bv0, mfma16(BC4(e1x), bv1, zero4));
                float4v am2 = mfma16(BC4(d0y), bv0, mfma16(BC4(e1y), bv1, zero4));
                float4v ae  = mfma16(BC4(d0s), bv0, mfma16(BC4(e1s), bv1, zero4));
                float4v ap  = mfma16(BC4(d0p), bv0, mfma16(BC4(e1p), bv1, zero4));
                SSIM_ACC(am1, am2, ae, ap)
            }
            {   // rgp = 1
                float4v bm1 = mfma16(BC4(e1x), bv0, mfma16(BC4(f2x), bv1, zero4));
                float4v bm2 = mfma16(BC4(e1y), bv0, mfma16(BC4(f2y), bv1, zero4));
                float4v be  = mfma16(BC4(e1s), bv0, mfma16(BC4(f2s), bv1, zero4));
                float4v bp  = mfma16(BC4(e1p), bv0, mfma16(BC4(f2p), bv1, zero4));
                SSIM_ACC(bm1, bm2, be, bp)
            }
        }

        // ---- Phase C: barrier (drains t+1 loads — they flew all of B) ----
        __syncthreads();
        cur ^= 1;
    }

    // ---- Block reduction (once, after all 12 tiles) ----
    #pragma unroll
    for (int off = 32; off > 0; off >>= 1) {
        ssim_loc += __shfl_down(ssim_loc, off);
        l1_loc   += __shfl_down(l1_loc, off);
    }
    if (lane == 0) {
        red[w] = ssim_loc;
        red[4 + w] = l1_loc;
    }
    __syncthreads();
    if (tid == 0) {
        float ss = red[0] + red[1] + red[2] + red[3];
        float ll = red[4] + red[5] + red[6] + red[7];
        partials[blockIdx.x] = ss;
        partials[NPBLK + blockIdx.x] = ll;
    }
}

__global__ __launch_bounds__(256)
void finalize_kernel(const float* __restrict__ partials, float* __restrict__ out) {
    __shared__ double rs[4], rl[4];
    const int tid = threadIdx.x;
    double ss = 0.0, ll = 0.0;
    for (int i = tid; i < NPBLK; i += 256) {
        ss += (double)partials[i];
        ll += (double)partials[NPBLK + i];
    }
    #pragma unroll
    for (int off = 32; off > 0; off >>= 1) {
        ss += __shfl_down(ss, off);
        ll += __shfl_down(ll, off);
    }
    int wave = tid >> 6, lane = tid & 63;
    if (lane == 0) { rs[wave] = ss; rl[wave] = ll; }
    __syncthreads();
    if (tid == 0) {
        double sst = rs[0] + rs[1] + rs[2] + rs[3];
        double llt = rl[0] + rl[1] + rl[2] + rl[3];
        double invn = 1.0 / (double)NPIX;
        out[0] = (float)(llt * invn + (1.0 - sst * invn));
    }
}

extern "C" void kernel_launch(void* const* d_in, const int* in_sizes, int n_in,
                              void* d_out, int out_size, void* d_ws, size_t ws_size,
                              hipStream_t stream) {
    const float* x = (const float*)d_in[0];   // outputs
    const float* y = (const float*)d_in[1];   // labels
    float* out = (float*)d_out;
    float* partials = (float*)d_ws;           // 2*NPBLK*4 = 4,096 B

    ssim_pipe_kernel<<<dim3(NPBLK), dim3(256), 0, stream>>>(x, y, partials);
    finalize_kernel<<<1, dim3(256), 0, stream>>>(partials, out);
}

// Round 13
// 131.505 us; speedup vs baseline: 1.0012x; 1.0012x over previous
//
#include <hip/hip_runtime.h>
#include <hip/hip_bf16.h>
#include <math.h>

#define IMG 512
#define TW 64                     // output tile width
#define TH 64                     // output tile height (R13: was 32)
#define NBX 8                     // 512/64
#define NBY 8                     // 512/64
#define NIMG 48
#define NBLK (NBX * NBY * NIMG)   // 3072
#define NPIX (16LL * 3 * 512 * 512)

#define C1F 0.0001f
#define C2F 0.0009f

// R13: 64x64 tile on R10's winning structure (single tile/block, gl_lds f32
// staging, one drain barrier). R12 falsified intra-block pipelining (2
// blocks/CU -> 6.2 B/cyc vs R10's 5-block 7.0): delivered vmem throughput
// scales with resident issuing blocks, and HBM BW is NOT the gate (92MB =
// 15us << 41us). Remaining lever: staged bytes per output. 64x64 cuts halo
// from 1.72x to 1.52x (staged total 176 -> 152.8 MB) and amortizes B-frag
// gather/prologue/reduction over 2x pixels. LDS 2*25,600 = 51.2KB -> 3
// blocks/CU (12 waves); each block issues 50-chunk bursts (1.8x deeper
// than R10). SR=84 keeps the free 2-way bank pattern (m136).
// Geometry: 5 H-conv row groups (rg4 rows 64..79 clamp to 73 — rows 74+
// feed only zero v-taps g[k+16-n]>=11), 4 V-conv pairs, L1 rows [5,68].
// Tripwires: WRITE_SIZE >> 1MB = spill; absmax must stay 0.0078125;
// dur >= 41us clean => tile-size axis dead, R10 is the keeper.

#define SR 84                     // LDS row stride in floats
#define SROWS 74                  // staged rows 0..73
#define CHUNKF 256                // floats per 1KB chunk (64 lanes * 4)
#define NCHUNK 25                 // ceil(74*84/256) = 24.3 -> 25
#define BUFFLOATS (NCHUNK * CHUNKF)   // 6400 (o >= 6216 = spare, never read)
#define REALFLOATS (SROWS * SR)       // 6216

typedef __attribute__((ext_vector_type(4))) short short4v;
typedef __attribute__((ext_vector_type(8))) short short8;
typedef __attribute__((ext_vector_type(4))) float float4v;
typedef __attribute__((ext_vector_type(2))) unsigned uint2v;
typedef __attribute__((ext_vector_type(4))) unsigned uint4v;

// 16x16x16 bf16 MFMA (device-verified _1k builtin on gfx950; host parse stub).
__device__ __forceinline__ float4v mfma16(short4v a, short4v b, float4v c) {
#if defined(__HIP_DEVICE_COMPILE__)
    return __builtin_amdgcn_mfma_f32_16x16x16bf16_1k(a, b, c, 0, 0, 0);
#else
    return c;   // host stub — never executed
#endif
}

// Async global->LDS 16B: lds dest = wave-uniform base + lane*16.
__device__ __forceinline__ void gl_lds16(const float* g, float* l) {
#if defined(__HIP_DEVICE_COMPILE__)
    __builtin_amdgcn_global_load_lds(
        (const __attribute__((address_space(1))) void*)g,
        (__attribute__((address_space(3))) void*)l, 16, 0, 0);
#else
    (void)g; (void)l;
#endif
}

// Gaussian window (sigma=1.5, ws=11), normalized (double-derived literals).
#define GW0 0.00102838f
#define GW1 0.00759877f
#define GW2 0.03600077f
#define GW3 0.10936069f
#define GW4 0.21300539f
#define GW5 0.26601172f

__device__ __forceinline__ unsigned short f2bf(float f) {
    unsigned u = __builtin_bit_cast(unsigned, f);
    u += 0x7FFF + ((u >> 16) & 1);            // RNE
    return (unsigned short)(u >> 16);
}
__device__ __forceinline__ unsigned pk2(float a, float b) {
    __hip_bfloat162 h = __float22bfloat162_rn(make_float2(a, b));
    unsigned u;
    __builtin_memcpy(&u, &h, 4);
    return u;
}

#define BC4(U) __builtin_bit_cast(short4v, U)

// H-conv of one row from the f32 panels: read 8 f32 of x and y, build the
// 4 bf16 channels in-register (R1's exact math), 4 MFMAs into named
// uint2v, owned-region L1 (q in {1,2}, srow in [5,68] — never clamped).
#define HCONV_F32(ROWE, SROWE, DX, DY, DS, DP)                                 \
    {                                                                          \
        const int srow_ = (SROWE);                                             \
        const int b_ = (ROWE) * SR + co;                                       \
        float4v x0 = *(const float4v*)&xb[b_];                                 \
        float4v x1 = *(const float4v*)&xb[b_ + 4];                             \
        float4v y0 = *(const float4v*)&yb[b_];                                 \
        float4v y1 = *(const float4v*)&yb[b_ + 4];                             \
        uint4v ux_ = (uint4v){pk2(x0[0], x0[1]), pk2(x0[2], x0[3]),            \
                              pk2(x1[0], x1[1]), pk2(x1[2], x1[3])};           \
        uint4v uy_ = (uint4v){pk2(y0[0], y0[1]), pk2(y0[2], y0[3]),            \
                              pk2(y1[0], y1[1]), pk2(y1[2], y1[3])};           \
        uint4v u2_ = (uint4v){                                                 \
            pk2(fmaf(x0[0],x0[0],y0[0]*y0[0]), fmaf(x0[1],x0[1],y0[1]*y0[1])), \
            pk2(fmaf(x0[2],x0[2],y0[2]*y0[2]), fmaf(x0[3],x0[3],y0[3]*y0[3])), \
            pk2(fmaf(x1[0],x1[0],y1[0]*y1[0]), fmaf(x1[1],x1[1],y1[1]*y1[1])), \
            pk2(fmaf(x1[2],x1[2],y1[2]*y1[2]), fmaf(x1[3],x1[3],y1[3]*y1[3]))};\
        uint4v u3_ = (uint4v){                                                 \
            pk2(x0[0]*y0[0], x0[1]*y0[1]), pk2(x0[2]*y0[2], x0[3]*y0[3]),      \
            pk2(x1[0]*y1[0], x1[1]*y1[1]), pk2(x1[2]*y1[2], x1[3]*y1[3])};     \
        float4v d_;                                                            \
        d_ = __builtin_amdgcn_mfma_f32_16x16x32_bf16(                          \
                 __builtin_bit_cast(short8, ux_), bh, zero4, 0, 0, 0);         \
        DX = (uint2v){pk2(d_[0], d_[1]), pk2(d_[2], d_[3])};                   \
        d_ = __builtin_amdgcn_mfma_f32_16x16x32_bf16(                          \
                 __builtin_bit_cast(short8, uy_), bh, zero4, 0, 0, 0);         \
        DY = (uint2v){pk2(d_[0], d_[1]), pk2(d_[2], d_[3])};                   \
        d_ = __builtin_amdgcn_mfma_f32_16x16x32_bf16(                          \
                 __builtin_bit_cast(short8, u2_), bh, zero4, 0, 0, 0);         \
        DS = (uint2v){pk2(d_[0], d_[1]), pk2(d_[2], d_[3])};                   \
        d_ = __builtin_amdgcn_mfma_f32_16x16x32_bf16(                          \
                 __builtin_bit_cast(short8, u3_), bh, zero4, 0, 0, 0);         \
        DP = (uint2v){pk2(d_[0], d_[1]), pk2(d_[2], d_[3])};                   \
        if ((unsigned)(q - 1) <= 1u && (unsigned)(srow_ - 5) <= 63u)           \
            l1_loc += fabsf(x0[0]-y0[0])+fabsf(x0[1]-y0[1])                    \
                    + fabsf(x0[2]-y0[2])+fabsf(x0[3]-y0[3])                    \
                    + fabsf(x1[0]-y1[0])+fabsf(x1[1]-y1[1])                    \
                    + fabsf(x1[2]-y1[2])+fabsf(x1[3]-y1[3]);                   \
    }

// V-conv pair + SSIM accumulate for one rgp.
#define VCONV_SSIM(AX, AY, AS, AP, BX, BY, BS, BP)                             \
    {                                                                          \
        float4v m1 = mfma16(BC4(AX), bv0, mfma16(BC4(BX), bv1, zero4));        \
        float4v m2 = mfma16(BC4(AY), bv0, mfma16(BC4(BY), bv1, zero4));        \
        float4v ee = mfma16(BC4(AS), bv0, mfma16(BC4(BS), bv1, zero4));        \
        float4v pp = mfma16(BC4(AP), bv0, mfma16(BC4(BP), bv1, zero4));        \
        _Pragma("unroll")                                                      \
        for (int r_ = 0; r_ < 4; ++r_) {                                       \
            float mu1 = m1[r_], mu2 = m2[r_];                                  \
            float e   = ee[r_], e12 = pp[r_];                                  \
            float p = mu1 * mu2;                                               \
            float s = fmaf(mu1, mu1, mu2 * mu2);                               \
            float num1 = fmaf(2.f, p, C1F);                                    \
            float num2 = fmaf(2.f, e12 - p, C2F);                              \
            float den1 = s + C1F;                                              \
            float den2 = (e - s) + C2F;                                        \
            ssim_loc = fmaf(num1 * num2,                                       \
                            __builtin_amdgcn_rcpf(den1 * den2), ssim_loc);     \
        }                                                                      \
    }

__global__ __launch_bounds__(256, 3)
void ssim_tile_kernel(const float* __restrict__ xg, const float* __restrict__ yg,
                      float* __restrict__ partials) {
    __shared__ float xb[BUFFLOATS];                 // 25,600 B
    __shared__ float yb[BUFFLOATS];                 // 25,600 B
    __shared__ unsigned short gwtbl[16];
    __shared__ float red[8];

    const int tid  = threadIdx.x;
    const int lane = tid & 63;
    const int w    = tid >> 6;        // wave 0..3 = colgroup
    const int q    = lane >> 4;       // quad 0..3
    const int n16  = lane & 15;

    const int img = blockIdx.z;
    const int r00  = blockIdx.y * TH - 5;   // global row of staged row 0
    const int c00a = blockIdx.x * TW - 8;   // global col of staged col 0
    const float* __restrict__ xi = xg + (size_t)img * (IMG * IMG);
    const float* __restrict__ yi = yg + (size_t)img * (IMG * IMG);

    // ---- bf16 Gaussian tap table (sealed by the staging barrier) ----
    if (tid < 16) {
        const float gwf[11] = {GW0, GW1, GW2, GW3, GW4, GW5, GW4, GW3, GW2, GW1, GW0};
        unsigned short v = 0;
        #pragma unroll
        for (int t = 0; t < 11; ++t)
            if (tid == t) v = f2bf(gwf[t]);
        gwtbl[tid] = v;
    }

    // ---- Issue ALL staging loads: 50 chunks of 1KB across 4 waves.
    //      Wave w: chunks w*13..w*13+12 (ck<50); ck<25 -> xb, else yb. ----
    #pragma unroll
    for (int k = 0; k < 13; ++k) {
        const int ck = w * 13 + k;                // wave-uniform
        if (ck < 2 * NCHUNK) {
            const bool isx = (ck < NCHUNK);
            const int c = isx ? ck : ck - NCHUNK; // wave-uniform
            const int o = c * CHUNKF + lane * 4;  // this lane's flat f32 slot
            const int row = o / SR;               // 0..76 (74..76 spare)
            const int col = o - row * SR;         // 0..83 (80..83 padding)
            const int gr = r00 + row, gc = c00a + col;
            if (((unsigned)gr < 512u) & ((unsigned)gc < 512u)) {
                const float* src = (isx ? xi : yi) + (size_t)gr * IMG + gc;
                float* dstb = (isx ? xb : yb) + c * CHUNKF;  // wave-uniform base
                gl_lds16(src, dstb);
            }
        }
    }

    // ---- Boundary blocks: zero exactly the NOT-loaded real slots
    //      (disjoint from async LDS writes -> race-free, no barrier). ----
    const bool interior = ((unsigned)(blockIdx.x - 1) <= 5u) &
                          ((unsigned)(blockIdx.y - 1) <= 5u);
    if (!interior) {
        const float4v z4 = {0.f, 0.f, 0.f, 0.f};
        for (int o = tid * 4; o < REALFLOATS; o += 1024) {
            int row = o / SR, col = o - row * SR;
            int gr = r00 + row, gc = c00a + col;
            if (!(((unsigned)gr < 512u) & ((unsigned)gc < 512u))) {
                *(float4v*)&xb[o] = z4;
                *(float4v*)&yb[o] = z4;
            }
        }
    }

    __syncthreads();   // compiler-emitted vmcnt(0)+lgkmcnt(0): the ONE drain

    // ---- B fragments from gwtbl (OOB index clamps to >=11 -> 0) ----
    short8 bh;
    short4v bv0, bv1;
    {
        int baseh = q * 8 - n16 - 3;
        #pragma unroll
        for (int j = 0; j < 8; ++j)
            bh[j] = (short)gwtbl[min((unsigned)(baseh + j), 15u)];
        int base0 = q * 4 - n16, base1 = q * 4 + 16 - n16;
        #pragma unroll
        for (int j = 0; j < 4; ++j) {
            bv0[j] = (short)gwtbl[min((unsigned)(base0 + j), 15u)];
            bv1[j] = (short)gwtbl[min((unsigned)(base1 + j), 15u)];
        }
    }

    // ---- H-conv: 5 row groups (rg4 rows 64..79 clamp to 73) ----
    const int co = w * 16 + q * 8;
    const float4v zero4 = {0.f, 0.f, 0.f, 0.f};
    float l1_loc = 0.f, ssim_loc = 0.f;
    uint2v d0x, d0y, d0s, d0p;      // rg0
    uint2v e1x, e1y, e1s, e1p;      // rg1
    uint2v f2x, f2y, f2s, f2p;      // rg2
    uint2v g3x, g3y, g3s, g3p;      // rg3
    uint2v h4x, h4y, h4s, h4p;      // rg4
    HCONV_F32(n16,               n16,      d0x, d0y, d0s, d0p)
    HCONV_F32(16 + n16,          16 + n16, e1x, e1y, e1s, e1p)
    HCONV_F32(32 + n16,          32 + n16, f2x, f2y, f2s, f2p)
    HCONV_F32(48 + n16,          48 + n16, g3x, g3y, g3s, g3p)
    HCONV_F32(min(64 + n16, 73), 64 + n16, h4x, h4y, h4s, h4p)

    // ---- V-conv: 4 pairs, out row rgp*16+n16, out col w*16+q*4+r ----
    VCONV_SSIM(d0x, d0y, d0s, d0p, e1x, e1y, e1s, e1p)   // rgp 0
    VCONV_SSIM(e1x, e1y, e1s, e1p, f2x, f2y, f2s, f2p)   // rgp 1
    VCONV_SSIM(f2x, f2y, f2s, f2p, g3x, g3y, g3s, g3p)   // rgp 2
    VCONV_SSIM(g3x, g3y, g3s, g3p, h4x, h4y, h4s, h4p)   // rgp 3

    // ---- Block reduction ----
    #pragma unroll
    for (int off = 32; off > 0; off >>= 1) {
        ssim_loc += __shfl_down(ssim_loc, off);
        l1_loc   += __shfl_down(l1_loc, off);
    }
    if (lane == 0) {
        red[w] = ssim_loc;
        red[4 + w] = l1_loc;
    }
    __syncthreads();
    if (tid == 0) {
        float ss = red[0] + red[1] + red[2] + red[3];
        float ll = red[4] + red[5] + red[6] + red[7];
        int bid = blockIdx.x + NBX * (blockIdx.y + NBY * blockIdx.z);
        partials[bid] = ss;
        partials[NBLK + bid] = ll;
    }
}

__global__ __launch_bounds__(1024)
void finalize_kernel(const float* __restrict__ partials, float* __restrict__ out) {
    __shared__ double rs[16], rl[16];
    const int tid = threadIdx.x;
    double ss = 0.0, ll = 0.0;
    for (int i = tid; i < NBLK; i += 1024) {
        ss += (double)partials[i];
        ll += (double)partials[NBLK + i];
    }
    #pragma unroll
    for (int off = 32; off > 0; off >>= 1) {
        ss += __shfl_down(ss, off);
        ll += __shfl_down(ll, off);
    }
    int wave = tid >> 6, lane = tid & 63;
    if (lane == 0) { rs[wave] = ss; rl[wave] = ll; }
    __syncthreads();
    if (tid == 0) {
        double sst = 0.0, llt = 0.0;
        #pragma unroll
        for (int w = 0; w < 16; ++w) { sst += rs[w]; llt += rl[w]; }
        double invn = 1.0 / (double)NPIX;
        out[0] = (float)(llt * invn + (1.0 - sst * invn));
    }
}

extern "C" void kernel_launch(void* const* d_in, const int* in_sizes, int n_in,
                              void* d_out, int out_size, void* d_ws, size_t ws_size,
                              hipStream_t stream) {
    const float* x = (const float*)d_in[0];   // outputs
    const float* y = (const float*)d_in[1];   // labels
    float* out = (float*)d_out;
    float* partials = (float*)d_ws;           // 2*NBLK*4 = 24,576 B

    dim3 grid(NBX, NBY, NIMG);
    ssim_tile_kernel<<<grid, dim3(256), 0, stream>>>(x, y, partials);
    finalize_kernel<<<1, dim3(1024), 0, stream>>>(partials, out);
}